// Round 2
// baseline (510.540 us; speedup 1.0000x reference)
//
#include <hip/hip_runtime.h>
#include <math.h>

#define E_DIM 1024
#define NHEAD 16
#define HDIM 64
#define FF_DIM 4096
#define NBATCH 2
#define SEQLEN 2048
#define NTOK 4096
#define LN_EPS 1e-5f

typedef unsigned short bfu;                                   // raw bf16 bits
typedef __attribute__((ext_vector_type(8))) short bf16x8;     // MFMA A/B frag (4 VGPR)
typedef __attribute__((ext_vector_type(4))) float f32x4;      // MFMA C/D frag

static __device__ __forceinline__ bfu f2bf(float f) {
  unsigned u = __float_as_uint(f);
  return (bfu)((u + 0x7fffu + ((u >> 16) & 1u)) >> 16);       // RNE, finite inputs
}

// ---------------- weight transpose + fp32 -> bf16 ----------------
// W[R][C] fp32  ->  Wt[C][R] bf16
__global__ __launch_bounds__(256) void transpose_cvt(
    const float* __restrict__ W, bfu* __restrict__ Wt, int R, int C) {
  __shared__ float t[32][33];
  int c0 = blockIdx.x * 32, r0 = blockIdx.y * 32;
#pragma unroll
  for (int i = 0; i < 32; i += 8)
    t[threadIdx.y + i][threadIdx.x] =
        W[(size_t)(r0 + threadIdx.y + i) * C + c0 + threadIdx.x];
  __syncthreads();
#pragma unroll
  for (int i = 0; i < 32; i += 8)
    Wt[(size_t)(c0 + threadIdx.y + i) * R + r0 + threadIdx.x] =
        f2bf(t[threadIdx.x][threadIdx.y + i]);
}

// ---------------- layernorm: fp32 [rows][1024] -> bf16 ----------------
__global__ __launch_bounds__(256) void ln_kernel(
    const float* __restrict__ x, const float* __restrict__ g,
    const float* __restrict__ b, bfu* __restrict__ out) {
  int row = blockIdx.x;
  float4 v = reinterpret_cast<const float4*>(x + (size_t)row * E_DIM)[threadIdx.x];
  float s = v.x + v.y + v.z + v.w;
  float s2 = v.x * v.x + v.y * v.y + v.z * v.z + v.w * v.w;
#pragma unroll
  for (int off = 1; off < 64; off <<= 1) {
    s += __shfl_xor(s, off);
    s2 += __shfl_xor(s2, off);
  }
  __shared__ float red[8];
  int wv = threadIdx.x >> 6;
  if ((threadIdx.x & 63) == 0) { red[wv] = s; red[4 + wv] = s2; }
  __syncthreads();
  s = red[0] + red[1] + red[2] + red[3];
  s2 = red[4] + red[5] + red[6] + red[7];
  float mu = s * (1.f / E_DIM);
  float var = s2 * (1.f / E_DIM) - mu * mu;
  float rs = rsqrtf(var + LN_EPS);
  int c = threadIdx.x * 4;
  ushort4 o;
  o.x = f2bf((v.x - mu) * rs * g[c + 0] + b[c + 0]);
  o.y = f2bf((v.y - mu) * rs * g[c + 1] + b[c + 1]);
  o.z = f2bf((v.z - mu) * rs * g[c + 2] + b[c + 2]);
  o.w = f2bf((v.w - mu) * rs * g[c + 3] + b[c + 3]);
  reinterpret_cast<ushort4*>(out + (size_t)row * E_DIM)[threadIdx.x] = o;
}

// ---------------- GEMM: C[M,N] = A[M,K](bf16) * Bt[N,K]^T(bf16) + epilogue ----
// EP 0: qkv scatter (+bias, q*0.125)  1: proj (+bias+resid -> f32)
// EP 2: fc1 (+bias, exact gelu -> bf16)  3: fc2 (+bias+resid -> f32)
template <int EP>
__global__ __launch_bounds__(256) void gemm_kernel(
    const bfu* __restrict__ A, const bfu* __restrict__ Bt,
    int M, int N, int K,
    const float* __restrict__ bias, const float* __restrict__ resid,
    float* __restrict__ outf, bfu* __restrict__ outb,
    bfu* __restrict__ qo, bfu* __restrict__ ko, bfu* __restrict__ vo) {
  __shared__ __align__(16) bfu As[128][72];   // pad 8: 144B row stride
  __shared__ __align__(16) bfu Bs[128][72];
  const int tid = threadIdx.x;
  const int lane = tid & 63, wv = tid >> 6;
  const int wr = (wv >> 1) * 64, wc = (wv & 1) * 64;
  const int m0 = blockIdx.y * 128, n0 = blockIdx.x * 128;

  f32x4 acc[4][4];
#pragma unroll
  for (int i = 0; i < 4; i++)
#pragma unroll
    for (int j = 0; j < 4; j++) acc[i][j] = (f32x4){0.f, 0.f, 0.f, 0.f};

  const int srow = tid >> 3, scol = (tid & 7) * 8;
  for (int k0 = 0; k0 < K; k0 += 64) {
#pragma unroll
    for (int i = 0; i < 4; i++) {
      int r = srow + i * 32;
      *reinterpret_cast<bf16x8*>(&As[r][scol]) =
          *reinterpret_cast<const bf16x8*>(A + (size_t)(m0 + r) * K + k0 + scol);
      *reinterpret_cast<bf16x8*>(&Bs[r][scol]) =
          *reinterpret_cast<const bf16x8*>(Bt + (size_t)(n0 + r) * K + k0 + scol);
    }
    __syncthreads();
#pragma unroll
    for (int kk = 0; kk < 2; kk++) {
      const int krd = kk * 32 + (lane >> 4) * 8;
      bf16x8 af[4], bfr[4];
#pragma unroll
      for (int i = 0; i < 4; i++) {
        af[i] = *reinterpret_cast<const bf16x8*>(&As[wr + i * 16 + (lane & 15)][krd]);
        bfr[i] = *reinterpret_cast<const bf16x8*>(&Bs[wc + i * 16 + (lane & 15)][krd]);
      }
#pragma unroll
      for (int i = 0; i < 4; i++)
#pragma unroll
        for (int j = 0; j < 4; j++)
          acc[i][j] = __builtin_amdgcn_mfma_f32_16x16x32_bf16(af[i], bfr[j], acc[i][j], 0, 0, 0);
    }
    __syncthreads();
  }

  const int cr = (lane >> 4) * 4, cc = lane & 15;
#pragma unroll
  for (int i = 0; i < 4; i++) {
#pragma unroll
    for (int j = 0; j < 4; j++) {
      const int gn = n0 + wc + j * 16 + cc;
      const float bb = bias[gn];
#pragma unroll
      for (int r = 0; r < 4; r++) {
        const int gm = m0 + wr + i * 16 + cr + r;
        float val = acc[i][j][r] + bb;
        if (EP == 0) {
          int which = gn >> 10, rem = gn & 1023;
          int hh = rem >> 6, dd = rem & 63;
          int b_ = gm >> 11, nn = gm & 2047;
          size_t dst = (((size_t)(b_ * NHEAD + hh)) * SEQLEN + nn) * HDIM + dd;
          if (which == 0) qo[dst] = f2bf(val * 0.125f);   // fold 1/sqrt(D)
          else if (which == 1) ko[dst] = f2bf(val);
          else vo[dst] = f2bf(val);
        } else if (EP == 1) {
          outf[(size_t)gm * N + gn] = val + resid[(size_t)gm * N + gn];
        } else if (EP == 2) {
          outb[(size_t)gm * N + gn] = f2bf(0.5f * val * (1.f + erff(val * 0.70710678f)));
        } else {
          outf[(size_t)gm * N + gn] = val + resid[(size_t)gm * N + gn];
        }
      }
    }
  }
}

// ---------------- flash attention (bf16 q/k/v in [B,H,N,D], out [B,N,E] bf16) --
__global__ __launch_bounds__(256) void attn_kernel(
    const bfu* __restrict__ q, const bfu* __restrict__ kbuf,
    const bfu* __restrict__ vbuf, bfu* __restrict__ o) {
  __shared__ __align__(16) bfu Ks[32][72];      // K tile, row-major, pad
  __shared__ __align__(16) bfu Vt[64][40];      // V^T tile [d][kv]
  __shared__ __align__(16) bfu Ps[4][16][40];   // per-wave P tile [q][kv]

  const int bh = blockIdx.y;                    // b*H + h
  const int q0 = blockIdx.x * 64;
  const int tid = threadIdx.x, lane = tid & 63, wv = tid >> 6;
  const size_t base = (size_t)bh * SEQLEN * HDIM;
  const bfu* qp = q + base;
  const bfu* kp = kbuf + base;
  const bfu* vp = vbuf + base;

  // Q fragments for this wave's 16 rows (already scaled by 1/8)
  const int qr = q0 + wv * 16 + (lane & 15);
  bf16x8 qf[2];
  qf[0] = *reinterpret_cast<const bf16x8*>(qp + (size_t)qr * HDIM + (lane >> 4) * 8);
  qf[1] = *reinterpret_cast<const bf16x8*>(qp + (size_t)qr * HDIM + 32 + (lane >> 4) * 8);

  float mrun[4], lrun[4];
  f32x4 oacc[4];
#pragma unroll
  for (int r = 0; r < 4; r++) { mrun[r] = -1e30f; lrun[r] = 0.f; }
#pragma unroll
  for (int d = 0; d < 4; d++) oacc[d] = (f32x4){0.f, 0.f, 0.f, 0.f};

  const int ksr = tid >> 3, ksc = (tid & 7) * 8;   // K staging map
  const int vsr = tid & 31, vsc = (tid >> 5) * 8;  // V staging map

  for (int kt = 0; kt < SEQLEN; kt += 32) {
    *reinterpret_cast<bf16x8*>(&Ks[ksr][ksc]) =
        *reinterpret_cast<const bf16x8*>(kp + (size_t)(kt + ksr) * HDIM + ksc);
    bf16x8 vvv = *reinterpret_cast<const bf16x8*>(vp + (size_t)(kt + vsr) * HDIM + vsc);
#pragma unroll
    for (int j = 0; j < 8; j++) Vt[vsc + j][vsr] = (bfu)(unsigned short)vvv[j];
    __syncthreads();

    // S[16 q][32 k] = Q * K^T
    f32x4 s[2];
#pragma unroll
    for (int kc = 0; kc < 2; kc++) {
      f32x4 a = (f32x4){0.f, 0.f, 0.f, 0.f};
#pragma unroll
      for (int kk = 0; kk < 2; kk++) {
        bf16x8 kf = *reinterpret_cast<const bf16x8*>(
            &Ks[kc * 16 + (lane & 15)][kk * 32 + (lane >> 4) * 8]);
        a = __builtin_amdgcn_mfma_f32_16x16x32_bf16(qf[kk], kf, a, 0, 0, 0);
      }
      s[kc] = a;
    }

    // online softmax; lane owns q-rows (lane>>4)*4+r at k-col (lane&15)+16*kc
#pragma unroll
    for (int r = 0; r < 4; r++) {
      float t = fmaxf(s[0][r], s[1][r]);
#pragma unroll
      for (int off = 1; off < 16; off <<= 1) t = fmaxf(t, __shfl_xor(t, off));
      float mnew = fmaxf(mrun[r], t);
      float alpha = __expf(mrun[r] - mnew);
      mrun[r] = mnew;
      float p0 = __expf(s[0][r] - mnew);
      float p1 = __expf(s[1][r] - mnew);
      float ps = p0 + p1;
#pragma unroll
      for (int off = 1; off < 16; off <<= 1) ps += __shfl_xor(ps, off);
      lrun[r] = lrun[r] * alpha + ps;
#pragma unroll
      for (int d = 0; d < 4; d++) oacc[d][r] *= alpha;
      int qrow = (lane >> 4) * 4 + r;
      Ps[wv][qrow][lane & 15] = f2bf(p0);
      Ps[wv][qrow][(lane & 15) + 16] = f2bf(p1);
    }
    __syncthreads();

    // O += P * V
    bf16x8 pf = *reinterpret_cast<const bf16x8*>(&Ps[wv][lane & 15][(lane >> 4) * 8]);
#pragma unroll
    for (int d = 0; d < 4; d++) {
      bf16x8 vf = *reinterpret_cast<const bf16x8*>(
          &Vt[d * 16 + (lane & 15)][(lane >> 4) * 8]);
      oacc[d] = __builtin_amdgcn_mfma_f32_16x16x32_bf16(pf, vf, oacc[d], 0, 0, 0);
    }
    __syncthreads();
  }

  // write O / l  -> out[b, n, h*64 + d]  (bf16)
  int b_ = bh >> 4, hh = bh & 15;
#pragma unroll
  for (int d = 0; d < 4; d++) {
#pragma unroll
    for (int r = 0; r < 4; r++) {
      int row = q0 + wv * 16 + (lane >> 4) * 4 + r;
      int col = hh * HDIM + d * 16 + (lane & 15);
      o[((size_t)(b_ * SEQLEN + row)) * E_DIM + col] = f2bf(oacc[d][r] / lrun[r]);
    }
  }
}

extern "C" void kernel_launch(void* const* d_in, const int* in_sizes, int n_in,
                              void* d_out, int out_size, void* d_ws, size_t ws_size,
                              hipStream_t stream) {
  (void)in_sizes; (void)n_in; (void)out_size; (void)ws_size;
  const float* x      = (const float*)d_in[0];
  const float* ln1_g  = (const float*)d_in[1];
  const float* ln1_b  = (const float*)d_in[2];
  const float* qkv_w  = (const float*)d_in[3];
  const float* qkv_b  = (const float*)d_in[4];
  const float* proj_w = (const float*)d_in[5];
  const float* proj_b = (const float*)d_in[6];
  const float* ln2_g  = (const float*)d_in[7];
  const float* ln2_b  = (const float*)d_in[8];
  const float* fc1_w  = (const float*)d_in[9];
  const float* fc1_b  = (const float*)d_in[10];
  const float* fc2_w  = (const float*)d_in[11];
  const float* fc2_b  = (const float*)d_in[12];
  float* out = (float*)d_out;

  char* p = (char*)d_ws;
  auto carve = [&](size_t n) { char* r = p; p += (n + 255) & ~(size_t)255; return r; };
  bfu* qkv_wt  = (bfu*)carve((size_t)3 * E_DIM * E_DIM * 2);   // [3E, E]
  bfu* proj_wt = (bfu*)carve((size_t)E_DIM * E_DIM * 2);       // [E, E]
  bfu* fc1_wt  = (bfu*)carve((size_t)FF_DIM * E_DIM * 2);      // [FF, E]
  bfu* fc2_wt  = (bfu*)carve((size_t)E_DIM * FF_DIM * 2);      // [E, FF]
  bfu* hbuf    = (bfu*)carve((size_t)NTOK * E_DIM * 2);        // LN out (reused)
  bfu* region  = (bfu*)carve((size_t)NTOK * FF_DIM * 2);       // q,k,v,ao | h3
  float* x1    = (float*)carve((size_t)NTOK * E_DIM * 4);      // post-attn residual
  bfu* qb = region;
  bfu* kb = region + (size_t)NTOK * E_DIM;
  bfu* vb = region + (size_t)2 * NTOK * E_DIM;
  bfu* ao = region + (size_t)3 * NTOK * E_DIM;
  bfu* h3 = region;                                            // aliases q/k/v/ao

  dim3 tb(32, 8);
  transpose_cvt<<<dim3(3 * E_DIM / 32, E_DIM / 32), tb, 0, stream>>>(qkv_w, qkv_wt, E_DIM, 3 * E_DIM);
  transpose_cvt<<<dim3(E_DIM / 32, E_DIM / 32), tb, 0, stream>>>(proj_w, proj_wt, E_DIM, E_DIM);
  transpose_cvt<<<dim3(FF_DIM / 32, E_DIM / 32), tb, 0, stream>>>(fc1_w, fc1_wt, E_DIM, FF_DIM);
  transpose_cvt<<<dim3(E_DIM / 32, FF_DIM / 32), tb, 0, stream>>>(fc2_w, fc2_wt, FF_DIM, E_DIM);

  ln_kernel<<<NTOK, 256, 0, stream>>>(x, ln1_g, ln1_b, hbuf);
  gemm_kernel<0><<<dim3(3 * E_DIM / 128, NTOK / 128), 256, 0, stream>>>(
      hbuf, qkv_wt, NTOK, 3 * E_DIM, E_DIM, qkv_b, nullptr, nullptr, nullptr, qb, kb, vb);
  attn_kernel<<<dim3(SEQLEN / 64, NBATCH * NHEAD), 256, 0, stream>>>(qb, kb, vb, ao);
  gemm_kernel<1><<<dim3(E_DIM / 128, NTOK / 128), 256, 0, stream>>>(
      ao, proj_wt, NTOK, E_DIM, E_DIM, proj_b, x, x1, nullptr, nullptr, nullptr, nullptr);
  ln_kernel<<<NTOK, 256, 0, stream>>>(x1, ln2_g, ln2_b, hbuf);
  gemm_kernel<2><<<dim3(FF_DIM / 128, NTOK / 128), 256, 0, stream>>>(
      hbuf, fc1_wt, NTOK, FF_DIM, E_DIM, fc1_b, nullptr, nullptr, h3, nullptr, nullptr, nullptr);
  gemm_kernel<3><<<dim3(E_DIM / 128, NTOK / 128), 256, 0, stream>>>(
      h3, fc2_wt, NTOK, E_DIM, FF_DIM, fc2_b, x1, out, nullptr, nullptr, nullptr, nullptr);
}

// Round 4
// 481.456 us; speedup vs baseline: 1.0604x; 1.0604x over previous
//
#include <hip/hip_runtime.h>
#include <math.h>

#define E_DIM 1024
#define NHEAD 16
#define HDIM 64
#define FF_DIM 4096
#define NBATCH 2
#define SEQLEN 2048
#define NTOK 4096
#define LN_EPS 1e-5f

typedef unsigned short bfu;                                   // raw bf16 bits
typedef __attribute__((ext_vector_type(8))) short bf16x8;     // MFMA A/B frag (4 VGPR)
typedef __attribute__((ext_vector_type(4))) float f32x4;      // MFMA C/D frag

static __device__ __forceinline__ bfu f2bf(float f) {
  unsigned u = __float_as_uint(f);
  return (bfu)((u + 0x7fffu + ((u >> 16) & 1u)) >> 16);       // RNE, finite inputs
}

// async global->LDS, 16B per lane: lane l writes ldsbase + l*16 bytes.
static __device__ __forceinline__ void gld16(const bfu* g, bfu* l) {
  __builtin_amdgcn_global_load_lds(
      (const __attribute__((address_space(1))) void*)g,
      (__attribute__((address_space(3))) void*)l, 16, 0, 0);
}

// ---------------- weight transpose + fp32 -> bf16 ----------------
__global__ __launch_bounds__(256) void transpose_cvt(
    const float* __restrict__ W, bfu* __restrict__ Wt, int R, int C) {
  __shared__ float t[32][33];
  int c0 = blockIdx.x * 32, r0 = blockIdx.y * 32;
#pragma unroll
  for (int i = 0; i < 32; i += 8)
    t[threadIdx.y + i][threadIdx.x] =
        W[(size_t)(r0 + threadIdx.y + i) * C + c0 + threadIdx.x];
  __syncthreads();
#pragma unroll
  for (int i = 0; i < 32; i += 8)
    Wt[(size_t)(c0 + threadIdx.y + i) * R + r0 + threadIdx.x] =
        f2bf(t[threadIdx.x][threadIdx.y + i]);
}

// ---------------- layernorm: fp32 [rows][1024] -> bf16 ----------------
__global__ __launch_bounds__(256) void ln_kernel(
    const float* __restrict__ x, const float* __restrict__ g,
    const float* __restrict__ b, bfu* __restrict__ out) {
  int row = blockIdx.x;
  float4 v = reinterpret_cast<const float4*>(x + (size_t)row * E_DIM)[threadIdx.x];
  float s = v.x + v.y + v.z + v.w;
  float s2 = v.x * v.x + v.y * v.y + v.z * v.z + v.w * v.w;
#pragma unroll
  for (int off = 1; off < 64; off <<= 1) {
    s += __shfl_xor(s, off);
    s2 += __shfl_xor(s2, off);
  }
  __shared__ float red[8];
  int wv = threadIdx.x >> 6;
  if ((threadIdx.x & 63) == 0) { red[wv] = s; red[4 + wv] = s2; }
  __syncthreads();
  s = red[0] + red[1] + red[2] + red[3];
  s2 = red[4] + red[5] + red[6] + red[7];
  float mu = s * (1.f / E_DIM);
  float var = s2 * (1.f / E_DIM) - mu * mu;
  float rs = rsqrtf(var + LN_EPS);
  int c = threadIdx.x * 4;
  ushort4 o;
  o.x = f2bf((v.x - mu) * rs * g[c + 0] + b[c + 0]);
  o.y = f2bf((v.y - mu) * rs * g[c + 1] + b[c + 1]);
  o.z = f2bf((v.z - mu) * rs * g[c + 2] + b[c + 2]);
  o.w = f2bf((v.w - mu) * rs * g[c + 3] + b[c + 3]);
  reinterpret_cast<ushort4*>(out + (size_t)row * E_DIM)[threadIdx.x] = o;
}

// ---------------- GEMM (m97 structure): C[M,N] = A * Bt^T + epilogue ----------
// EP 0: qkv scatter (+bias, q*0.125)  1: proj (+bias+resid -> f32)
// EP 2: fc1 (+bias, exact gelu -> bf16)  3: fc2 (+bias+resid -> f32)
template <int EP, int BN>
__global__ __launch_bounds__(256) void gemm_kernel(
    const bfu* __restrict__ A, const bfu* __restrict__ Bt,
    int M, int N, int K,
    const float* __restrict__ bias, const float* __restrict__ resid,
    float* __restrict__ outf, bfu* __restrict__ outb,
    bfu* __restrict__ qo, bfu* __restrict__ ko, bfu* __restrict__ vo) {
  constexpr int NJ = BN / 32;                 // col frags per wave (2x2 wave grid)
  __shared__ __align__(16) bfu As[128][64];   // linear: required by global_load_lds
  __shared__ __align__(16) bfu Bs[BN][64];
  const int tid = threadIdx.x;
  const int lane = tid & 63, wv = tid >> 6;
  const int wr = (wv >> 1) * 64, wc = (wv & 1) * (BN / 2);
  const int m0 = blockIdx.y * 128, n0 = blockIdx.x * BN;

  f32x4 acc[4][NJ];
#pragma unroll
  for (int i = 0; i < 4; i++)
#pragma unroll
    for (int j = 0; j < NJ; j++) acc[i][j] = (f32x4){0.f, 0.f, 0.f, 0.f};

  const int sr = lane >> 3, sc = (lane & 7) * 8;   // per-lane src within 8-row chunk
  for (int k0 = 0; k0 < K; k0 += 64) {
#pragma unroll
    for (int c = 0; c < 4; c++) {               // A rows [wv*32, wv*32+32)
      int r = wv * 32 + c * 8;
      gld16(A + (size_t)(m0 + r + sr) * K + k0 + sc, &As[r][0]);
    }
#pragma unroll
    for (int c = 0; c < BN / 32; c++) {         // B rows, BN/32 chunks per wave
      int r = wv * (BN / 4) + c * 8;
      gld16(Bt + (size_t)(n0 + r + sr) * K + k0 + sc, &Bs[r][0]);
    }
    __syncthreads();                            // drains vmcnt -> tiles ready
#pragma unroll
    for (int kk = 0; kk < 2; kk++) {
      const int krd = kk * 32 + (lane >> 4) * 8;
      bf16x8 af[4], bfr[NJ];
#pragma unroll
      for (int i = 0; i < 4; i++)
        af[i] = *reinterpret_cast<const bf16x8*>(&As[wr + i * 16 + (lane & 15)][krd]);
#pragma unroll
      for (int j = 0; j < NJ; j++)
        bfr[j] = *reinterpret_cast<const bf16x8*>(&Bs[wc + j * 16 + (lane & 15)][krd]);
#pragma unroll
      for (int i = 0; i < 4; i++)
#pragma unroll
        for (int j = 0; j < NJ; j++)
          acc[i][j] = __builtin_amdgcn_mfma_f32_16x16x32_bf16(af[i], bfr[j], acc[i][j], 0, 0, 0);
    }
    __syncthreads();
  }

  const int cr = (lane >> 4) * 4, cc = lane & 15;
#pragma unroll
  for (int i = 0; i < 4; i++) {
#pragma unroll
    for (int j = 0; j < NJ; j++) {
      const int gn = n0 + wc + j * 16 + cc;
      const float bb = bias[gn];
#pragma unroll
      for (int r = 0; r < 4; r++) {
        const int gm = m0 + wr + i * 16 + cr + r;
        float val = acc[i][j][r] + bb;
        if (EP == 0) {
          int which = gn >> 10, rem = gn & 1023;
          int hh = rem >> 6, dd = rem & 63;
          int b_ = gm >> 11, nn = gm & 2047;
          size_t dst = (((size_t)(b_ * NHEAD + hh)) * SEQLEN + nn) * HDIM + dd;
          if (which == 0) qo[dst] = f2bf(val * 0.125f);   // fold 1/sqrt(D)
          else if (which == 1) ko[dst] = f2bf(val);
          else vo[dst] = f2bf(val);
        } else if (EP == 1) {
          outf[(size_t)gm * N + gn] = val + resid[(size_t)gm * N + gn];
        } else if (EP == 2) {
          outb[(size_t)gm * N + gn] = f2bf(0.5f * val * (1.f + erff(val * 0.70710678f)));
        } else {
          outf[(size_t)gm * N + gn] = val + resid[(size_t)gm * N + gn];
        }
      }
    }
  }
}

// ---------------- flash attention: KVBLK=64, defer-max, swizzled K ----------
// K LDS swizzle (element space): f(row, ce) = ce ^ ((row&7)<<3), applied on the
// global SOURCE address at staging (LDS dest stays linear for global_load_lds)
// and on the READ address in QK^T. Involution -> both sides consistent.
__global__ __launch_bounds__(256) void attn_kernel(
    const bfu* __restrict__ q, const bfu* __restrict__ kbuf,
    const bfu* __restrict__ vbuf, bfu* __restrict__ o) {
  __shared__ __align__(16) bfu Ks[64][64];      // linear (global_load_lds dest)
  __shared__ __align__(16) bfu Vt[64][72];      // V^T [d][kv], pad 8
  __shared__ __align__(16) bfu Ps[4][16][72];   // per-wave P [q][kv], pad 8

  const int bh = blockIdx.y;                    // b*H + h
  const int q0 = blockIdx.x * 64;
  const int tid = threadIdx.x, lane = tid & 63, wv = tid >> 6;
  const size_t base = (size_t)bh * SEQLEN * HDIM;
  const bfu* qp = q + base;
  const bfu* kp = kbuf + base;
  const bfu* vp = vbuf + base;

  // Q fragments for this wave's 16 rows (pre-scaled by 1/8 at qkv epilogue)
  const int qr = q0 + wv * 16 + (lane & 15);
  bf16x8 qf[2];
  qf[0] = *reinterpret_cast<const bf16x8*>(qp + (size_t)qr * HDIM + (lane >> 4) * 8);
  qf[1] = *reinterpret_cast<const bf16x8*>(qp + (size_t)qr * HDIM + 32 + (lane >> 4) * 8);

  float mrun[4], lrun[4];
  f32x4 oacc[4];
#pragma unroll
  for (int r = 0; r < 4; r++) { mrun[r] = -1e30f; lrun[r] = 0.f; }
#pragma unroll
  for (int d = 0; d < 4; d++) oacc[d] = (f32x4){0.f, 0.f, 0.f, 0.f};

  const int sr = lane >> 3;                          // K staging row within chunk
  const int scs = ((lane & 7) ^ (sr & 7)) * 8;       // pre-swizzled source col
  const int vrow = tid & 63, vcb = (tid >> 6) * 16;  // V staging

  for (int kt = 0; kt < SEQLEN; kt += 64) {
    // K tile via async DMA: wave wv stages chunks {2wv, 2wv+1} (8 rows each)
#pragma unroll
    for (int c = 0; c < 2; c++) {
      int ch = wv * 2 + c;
      gld16(kp + (size_t)(kt + ch * 8 + sr) * HDIM + scs, &Ks[ch * 8][0]);
    }
    // V tile: reg-staged transpose; writes are 2-way at worst (64 lanes / row)
    bf16x8 v0 = *reinterpret_cast<const bf16x8*>(vp + (size_t)(kt + vrow) * HDIM + vcb);
    bf16x8 v1 = *reinterpret_cast<const bf16x8*>(vp + (size_t)(kt + vrow) * HDIM + vcb + 8);
#pragma unroll
    for (int j = 0; j < 8; j++) {
      Vt[vcb + j][vrow] = (bfu)(unsigned short)v0[j];
      Vt[vcb + 8 + j][vrow] = (bfu)(unsigned short)v1[j];
    }
    __syncthreads();

    // S[16 q][64 k] = Q K^T   (4 col-tiles of 16); K read swizzled by f
    f32x4 s[4];
#pragma unroll
    for (int kc = 0; kc < 4; kc++) {
      f32x4 a = (f32x4){0.f, 0.f, 0.f, 0.f};
#pragma unroll
      for (int kk = 0; kk < 2; kk++) {
        int ce = (kk * 32 + (lane >> 4) * 8) ^ ((lane & 7) << 3);
        bf16x8 kf = *reinterpret_cast<const bf16x8*>(&Ks[kc * 16 + (lane & 15)][ce]);
        a = __builtin_amdgcn_mfma_f32_16x16x32_bf16(qf[kk], kf, a, 0, 0, 0);
      }
      s[kc] = a;
    }

    // online softmax, defer-max (THR=8): row r of this lane group
#pragma unroll
    for (int r = 0; r < 4; r++) {
      float t = fmaxf(fmaxf(s[0][r], s[1][r]), fmaxf(s[2][r], s[3][r]));
#pragma unroll
      for (int off = 1; off < 16; off <<= 1) t = fmaxf(t, __shfl_xor(t, off));
      if (t > mrun[r] + 8.f) {                  // rescale only on big max growth
        float alpha = __expf(mrun[r] - t);
        mrun[r] = t;
        lrun[r] *= alpha;
#pragma unroll
        for (int d = 0; d < 4; d++) oacc[d][r] *= alpha;
      }
      const float m = mrun[r];
      float p0 = __expf(s[0][r] - m), p1 = __expf(s[1][r] - m);
      float p2 = __expf(s[2][r] - m), p3 = __expf(s[3][r] - m);
      float ps = (p0 + p1) + (p2 + p3);
#pragma unroll
      for (int off = 1; off < 16; off <<= 1) ps += __shfl_xor(ps, off);
      lrun[r] += ps;
      const int qrow = (lane >> 4) * 4 + r, cb = lane & 15;
      Ps[wv][qrow][cb] = f2bf(p0);
      Ps[wv][qrow][16 + cb] = f2bf(p1);
      Ps[wv][qrow][32 + cb] = f2bf(p2);
      Ps[wv][qrow][48 + cb] = f2bf(p3);
    }
    // Ps is wave-private: DS ops within a wave are in-order -> no barrier

    // O += P V
    bf16x8 pf[2];
#pragma unroll
    for (int ks = 0; ks < 2; ks++)
      pf[ks] = *reinterpret_cast<const bf16x8*>(
          &Ps[wv][lane & 15][ks * 32 + (lane >> 4) * 8]);
#pragma unroll
    for (int d = 0; d < 4; d++) {
#pragma unroll
      for (int ks = 0; ks < 2; ks++) {
        bf16x8 vf = *reinterpret_cast<const bf16x8*>(
            &Vt[d * 16 + (lane & 15)][ks * 32 + (lane >> 4) * 8]);
        oacc[d] = __builtin_amdgcn_mfma_f32_16x16x32_bf16(pf[ks], vf, oacc[d], 0, 0, 0);
      }
    }
    __syncthreads();                            // protect Ks/Vt for next tile
  }

  // write O / l  -> out[b, n, h*64 + d]  (bf16)
  int b_ = bh >> 4, hh = bh & 15;
#pragma unroll
  for (int d = 0; d < 4; d++) {
#pragma unroll
    for (int r = 0; r < 4; r++) {
      int row = q0 + wv * 16 + (lane >> 4) * 4 + r;
      int col = hh * HDIM + d * 16 + (lane & 15);
      o[((size_t)(b_ * SEQLEN + row)) * E_DIM + col] = f2bf(oacc[d][r] / lrun[r]);
    }
  }
}

extern "C" void kernel_launch(void* const* d_in, const int* in_sizes, int n_in,
                              void* d_out, int out_size, void* d_ws, size_t ws_size,
                              hipStream_t stream) {
  (void)in_sizes; (void)n_in; (void)out_size; (void)ws_size;
  const float* x      = (const float*)d_in[0];
  const float* ln1_g  = (const float*)d_in[1];
  const float* ln1_b  = (const float*)d_in[2];
  const float* qkv_w  = (const float*)d_in[3];
  const float* qkv_b  = (const float*)d_in[4];
  const float* proj_w = (const float*)d_in[5];
  const float* proj_b = (const float*)d_in[6];
  const float* ln2_g  = (const float*)d_in[7];
  const float* ln2_b  = (const float*)d_in[8];
  const float* fc1_w  = (const float*)d_in[9];
  const float* fc1_b  = (const float*)d_in[10];
  const float* fc2_w  = (const float*)d_in[11];
  const float* fc2_b  = (const float*)d_in[12];
  float* out = (float*)d_out;

  char* p = (char*)d_ws;
  auto carve = [&](size_t n) { char* r = p; p += (n + 255) & ~(size_t)255; return r; };
  bfu* qkv_wt  = (bfu*)carve((size_t)3 * E_DIM * E_DIM * 2);   // [3E, E]
  bfu* proj_wt = (bfu*)carve((size_t)E_DIM * E_DIM * 2);       // [E, E]
  bfu* fc1_wt  = (bfu*)carve((size_t)FF_DIM * E_DIM * 2);      // [FF, E]
  bfu* fc2_wt  = (bfu*)carve((size_t)E_DIM * FF_DIM * 2);      // [E, FF]
  bfu* hbuf    = (bfu*)carve((size_t)NTOK * E_DIM * 2);        // LN out (reused)
  bfu* region  = (bfu*)carve((size_t)NTOK * FF_DIM * 2);       // q,k,v,ao | h3
  float* x1    = (float*)carve((size_t)NTOK * E_DIM * 4);      // post-attn residual
  bfu* qb = region;
  bfu* kb = region + (size_t)NTOK * E_DIM;
  bfu* vb = region + (size_t)2 * NTOK * E_DIM;
  bfu* ao = region + (size_t)3 * NTOK * E_DIM;
  bfu* h3 = region;                                            // aliases q/k/v/ao

  dim3 tb(32, 8);
  transpose_cvt<<<dim3(3 * E_DIM / 32, E_DIM / 32), tb, 0, stream>>>(qkv_w, qkv_wt, E_DIM, 3 * E_DIM);
  transpose_cvt<<<dim3(E_DIM / 32, E_DIM / 32), tb, 0, stream>>>(proj_w, proj_wt, E_DIM, E_DIM);
  transpose_cvt<<<dim3(FF_DIM / 32, E_DIM / 32), tb, 0, stream>>>(fc1_w, fc1_wt, E_DIM, FF_DIM);
  transpose_cvt<<<dim3(E_DIM / 32, FF_DIM / 32), tb, 0, stream>>>(fc2_w, fc2_wt, FF_DIM, E_DIM);

  ln_kernel<<<NTOK, 256, 0, stream>>>(x, ln1_g, ln1_b, hbuf);
  gemm_kernel<0, 128><<<dim3(3 * E_DIM / 128, NTOK / 128), 256, 0, stream>>>(
      hbuf, qkv_wt, NTOK, 3 * E_DIM, E_DIM, qkv_b, nullptr, nullptr, nullptr, qb, kb, vb);
  attn_kernel<<<dim3(SEQLEN / 64, NBATCH * NHEAD), 256, 0, stream>>>(qb, kb, vb, ao);
  gemm_kernel<1, 64><<<dim3(E_DIM / 64, NTOK / 128), 256, 0, stream>>>(
      ao, proj_wt, NTOK, E_DIM, E_DIM, proj_b, x, x1, nullptr, nullptr, nullptr, nullptr);
  ln_kernel<<<NTOK, 256, 0, stream>>>(x1, ln2_g, ln2_b, hbuf);
  gemm_kernel<2, 128><<<dim3(FF_DIM / 128, NTOK / 128), 256, 0, stream>>>(
      hbuf, fc1_wt, NTOK, FF_DIM, E_DIM, fc1_b, nullptr, nullptr, h3, nullptr, nullptr, nullptr);
  gemm_kernel<3, 64><<<dim3(E_DIM / 64, NTOK / 128), 256, 0, stream>>>(
      h3, fc2_wt, NTOK, E_DIM, FF_DIM, fc2_b, x1, out, nullptr, nullptr, nullptr, nullptr);
}

// Round 6
// 442.523 us; speedup vs baseline: 1.1537x; 1.0880x over previous
//
#include <hip/hip_runtime.h>
#include <math.h>

#define E_DIM 1024
#define NHEAD 16
#define HDIM 64
#define FF_DIM 4096
#define NBATCH 2
#define SEQLEN 2048
#define NTOK 4096
#define LN_EPS 1e-5f

typedef unsigned short bfu;                                   // raw bf16 bits
typedef __attribute__((ext_vector_type(8))) short bf16x8;     // MFMA A/B frag (4 VGPR)
typedef __attribute__((ext_vector_type(4))) float f32x4;      // MFMA C/D frag

static __device__ __forceinline__ bfu f2bf(float f) {
  unsigned u = __float_as_uint(f);
  return (bfu)((u + 0x7fffu + ((u >> 16) & 1u)) >> 16);       // RNE, finite inputs
}

// async global->LDS, 16B per lane: lane l writes ldsbase + l*16 bytes.
static __device__ __forceinline__ void gld16(const bfu* g, bfu* l) {
  __builtin_amdgcn_global_load_lds(
      (const __attribute__((address_space(1))) void*)g,
      (__attribute__((address_space(3))) void*)l, 16, 0, 0);
}

// ---------------- weight transpose + fp32 -> bf16 ----------------
__global__ __launch_bounds__(256) void transpose_cvt(
    const float* __restrict__ W, bfu* __restrict__ Wt, int R, int C) {
  __shared__ float t[32][33];
  int c0 = blockIdx.x * 32, r0 = blockIdx.y * 32;
#pragma unroll
  for (int i = 0; i < 32; i += 8)
    t[threadIdx.y + i][threadIdx.x] =
        W[(size_t)(r0 + threadIdx.y + i) * C + c0 + threadIdx.x];
  __syncthreads();
#pragma unroll
  for (int i = 0; i < 32; i += 8)
    Wt[(size_t)(c0 + threadIdx.y + i) * R + r0 + threadIdx.x] =
        f2bf(t[threadIdx.x][threadIdx.y + i]);
}

// ---------------- layernorm: fp32 [rows][1024] -> bf16 ----------------
__global__ __launch_bounds__(256) void ln_kernel(
    const float* __restrict__ x, const float* __restrict__ g,
    const float* __restrict__ b, bfu* __restrict__ out) {
  int row = blockIdx.x;
  float4 v = reinterpret_cast<const float4*>(x + (size_t)row * E_DIM)[threadIdx.x];
  float s = v.x + v.y + v.z + v.w;
  float s2 = v.x * v.x + v.y * v.y + v.z * v.z + v.w * v.w;
#pragma unroll
  for (int off = 1; off < 64; off <<= 1) {
    s += __shfl_xor(s, off);
    s2 += __shfl_xor(s2, off);
  }
  __shared__ float red[8];
  int wv = threadIdx.x >> 6;
  if ((threadIdx.x & 63) == 0) { red[wv] = s; red[4 + wv] = s2; }
  __syncthreads();
  s = red[0] + red[1] + red[2] + red[3];
  s2 = red[4] + red[5] + red[6] + red[7];
  float mu = s * (1.f / E_DIM);
  float var = s2 * (1.f / E_DIM) - mu * mu;
  float rs = rsqrtf(var + LN_EPS);
  int c = threadIdx.x * 4;
  ushort4 o;
  o.x = f2bf((v.x - mu) * rs * g[c + 0] + b[c + 0]);
  o.y = f2bf((v.y - mu) * rs * g[c + 1] + b[c + 1]);
  o.z = f2bf((v.z - mu) * rs * g[c + 2] + b[c + 2]);
  o.w = f2bf((v.w - mu) * rs * g[c + 3] + b[c + 3]);
  reinterpret_cast<ushort4*>(out + (size_t)row * E_DIM)[threadIdx.x] = o;
}

// ---------------- GEMM (m97 structure + XCD swizzle): C = A * Bt^T + epilogue --
// EP 0: qkv scatter (+bias, q*0.125)  1: proj (+bias+resid -> f32)
// EP 2: fc1 (+bias, exact gelu -> bf16)  3: fc2 (+bias+resid -> f32)
template <int EP, int BN>
__global__ __launch_bounds__(256) void gemm_kernel(
    const bfu* __restrict__ A, const bfu* __restrict__ Bt,
    int M, int N, int K,
    const float* __restrict__ bias, const float* __restrict__ resid,
    float* __restrict__ outf, bfu* __restrict__ outb,
    bfu* __restrict__ qo, bfu* __restrict__ ko, bfu* __restrict__ vo) {
  constexpr int NJ = BN / 32;                 // col frags per wave (2x2 wave grid)
  __shared__ __align__(16) bfu As[128][64];   // linear: required by global_load_lds
  __shared__ __align__(16) bfu Bs[BN][64];
  const int tid = threadIdx.x;
  const int lane = tid & 63, wv = tid >> 6;
  const int wr = (wv >> 1) * 64, wc = (wv & 1) * (BN / 2);
  // XCD-aware bijective swizzle (T1): contiguous logical chunk per XCD.
  const int gx = gridDim.x, nwg = gx * gridDim.y;
  const int hw = blockIdx.y * gx + blockIdx.x;
  const int lg = (hw & 7) * (nwg >> 3) + (hw >> 3);
  const int m0 = (lg / gx) * 128, n0 = (lg % gx) * BN;

  f32x4 acc[4][NJ];
#pragma unroll
  for (int i = 0; i < 4; i++)
#pragma unroll
    for (int j = 0; j < NJ; j++) acc[i][j] = (f32x4){0.f, 0.f, 0.f, 0.f};

  const int sr = lane >> 3, sc = (lane & 7) * 8;   // per-lane src within 8-row chunk
  for (int k0 = 0; k0 < K; k0 += 64) {
#pragma unroll
    for (int c = 0; c < 4; c++) {               // A rows [wv*32, wv*32+32)
      int r = wv * 32 + c * 8;
      gld16(A + (size_t)(m0 + r + sr) * K + k0 + sc, &As[r][0]);
    }
#pragma unroll
    for (int c = 0; c < BN / 32; c++) {         // B rows, BN/32 chunks per wave
      int r = wv * (BN / 4) + c * 8;
      gld16(Bt + (size_t)(n0 + r + sr) * K + k0 + sc, &Bs[r][0]);
    }
    __syncthreads();                            // drains vmcnt -> tiles ready
#pragma unroll
    for (int kk = 0; kk < 2; kk++) {
      const int krd = kk * 32 + (lane >> 4) * 8;
      bf16x8 af[4], bfr[NJ];
#pragma unroll
      for (int i = 0; i < 4; i++)
        af[i] = *reinterpret_cast<const bf16x8*>(&As[wr + i * 16 + (lane & 15)][krd]);
#pragma unroll
      for (int j = 0; j < NJ; j++)
        bfr[j] = *reinterpret_cast<const bf16x8*>(&Bs[wc + j * 16 + (lane & 15)][krd]);
#pragma unroll
      for (int i = 0; i < 4; i++)
#pragma unroll
        for (int j = 0; j < NJ; j++)
          acc[i][j] = __builtin_amdgcn_mfma_f32_16x16x32_bf16(af[i], bfr[j], acc[i][j], 0, 0, 0);
    }
    __syncthreads();
  }

  const int cr = (lane >> 4) * 4, cc = lane & 15;
#pragma unroll
  for (int i = 0; i < 4; i++) {
#pragma unroll
    for (int j = 0; j < NJ; j++) {
      const int gn = n0 + wc + j * 16 + cc;
      const float bb = bias[gn];
#pragma unroll
      for (int r = 0; r < 4; r++) {
        const int gm = m0 + wr + i * 16 + cr + r;
        float val = acc[i][j][r] + bb;
        if (EP == 0) {
          int which = gn >> 10, rem = gn & 1023;
          int hh = rem >> 6, dd = rem & 63;
          int b_ = gm >> 11, nn = gm & 2047;
          size_t dst = (((size_t)(b_ * NHEAD + hh)) * SEQLEN + nn) * HDIM + dd;
          if (which == 0) qo[dst] = f2bf(val * 0.125f);   // fold 1/sqrt(D)
          else if (which == 1) ko[dst] = f2bf(val);
          else vo[dst] = f2bf(val);
        } else if (EP == 1) {
          outf[(size_t)gm * N + gn] = val + resid[(size_t)gm * N + gn];
        } else if (EP == 2) {
          outb[(size_t)gm * N + gn] = f2bf(0.5f * val * (1.f + erff(val * 0.70710678f)));
        } else {
          outf[(size_t)gm * N + gn] = val + resid[(size_t)gm * N + gn];
        }
      }
    }
  }
}

// ---------------- flash attention: swapped QK^T, in-lane softmax -------------
// K LDS swizzle: f(row, ce) = ce ^ ((row&7)<<3) applied on global SOURCE at
// staging (LDS dest linear for global_load_lds) and on the READ in QK^T.
// QK^T computed as mfma(K, Q) -> S^T: lane holds S[kv(16 vals)][q=lane&15];
// softmax is in-lane + 2 shfl_xor; P stored as 4x ds_write_b64 (wave-private).
__global__ __launch_bounds__(256) void attn_kernel(
    const bfu* __restrict__ q, const bfu* __restrict__ kbuf,
    const bfu* __restrict__ vbuf, bfu* __restrict__ o) {
  __shared__ __align__(16) bfu Ks[64][64];      // linear (global_load_lds dest)
  __shared__ __align__(16) bfu Vt[64][72];      // V^T tile [d][kv], pad 8
  __shared__ __align__(16) bfu Ps[4][16][72];   // per-wave P [q][kv], pad 8

  // XCD swizzle: group q-tiles of the same head on one XCD (K/V L2 reuse)
  const int hw = blockIdx.y * gridDim.x + blockIdx.x;   // grid (32, 32)
  const int lg = (hw & 7) * 128 + (hw >> 3);
  const int bh = lg >> 5;                       // b*H + h
  const int q0 = (lg & 31) * 64;
  const int tid = threadIdx.x, lane = tid & 63, wv = tid >> 6;
  const size_t base = (size_t)bh * SEQLEN * HDIM;
  const bfu* qp = q + base;
  const bfu* kp = kbuf + base;
  const bfu* vp = vbuf + base;

  // Q fragments for this wave's 16 rows (pre-scaled by 1/8 at qkv epilogue)
  const int qr = q0 + wv * 16 + (lane & 15);
  bf16x8 qf[2];
  qf[0] = *reinterpret_cast<const bf16x8*>(qp + (size_t)qr * HDIM + (lane >> 4) * 8);
  qf[1] = *reinterpret_cast<const bf16x8*>(qp + (size_t)qr * HDIM + 32 + (lane >> 4) * 8);

  float mrun = -1e30f, lrun = 0.f;              // softmax state for q = lane&15
  f32x4 oacc[4];                                // O rows q' = (lane>>4)*4+r
#pragma unroll
  for (int d = 0; d < 4; d++) oacc[d] = (f32x4){0.f, 0.f, 0.f, 0.f};

  const int sr = lane >> 3;                          // K staging row within chunk
  const int scs = ((lane & 7) ^ (sr & 7)) * 8;       // pre-swizzled source col
  const int vrow = tid & 63, vcb = (tid >> 6) * 16;  // V staging

  for (int kt = 0; kt < SEQLEN; kt += 64) {
    // K tile via async DMA: wave wv stages chunks {2wv, 2wv+1} (8 rows each)
#pragma unroll
    for (int c = 0; c < 2; c++) {
      int ch = wv * 2 + c;
      gld16(kp + (size_t)(kt + ch * 8 + sr) * HDIM + scs, &Ks[ch * 8][0]);
    }
    // V tile: reg-staged transpose; writes conflict-free (64 lanes span a row)
    bf16x8 v0 = *reinterpret_cast<const bf16x8*>(vp + (size_t)(kt + vrow) * HDIM + vcb);
    bf16x8 v1 = *reinterpret_cast<const bf16x8*>(vp + (size_t)(kt + vrow) * HDIM + vcb + 8);
#pragma unroll
    for (int j = 0; j < 8; j++) {
      Vt[vcb + j][vrow] = (bfu)(unsigned short)v0[j];
      Vt[vcb + 8 + j][vrow] = (bfu)(unsigned short)v1[j];
    }
    __syncthreads();

    // S^T[kv][q] = mfma(K, Q): st[kc][r] = S[kv=kc*16+(lane>>4)*4+r][q=lane&15]
    f32x4 st[4];
    __builtin_amdgcn_s_setprio(1);
#pragma unroll
    for (int kc = 0; kc < 4; kc++) {
      f32x4 a = (f32x4){0.f, 0.f, 0.f, 0.f};
#pragma unroll
      for (int kk = 0; kk < 2; kk++) {
        int ce = (kk * 32 + (lane >> 4) * 8) ^ ((lane & 7) << 3);
        bf16x8 kf = *reinterpret_cast<const bf16x8*>(&Ks[kc * 16 + (lane & 15)][ce]);
        a = __builtin_amdgcn_mfma_f32_16x16x32_bf16(kf, qf[kk], a, 0, 0, 0);
      }
      st[kc] = a;
    }
    __builtin_amdgcn_s_setprio(0);

    // in-lane softmax over the 16 kv values, then 2 shfls to span all 64 kv
    float t0 = fmaxf(fmaxf(st[0][0], st[0][1]), fmaxf(st[0][2], st[0][3]));
    float t1 = fmaxf(fmaxf(st[1][0], st[1][1]), fmaxf(st[1][2], st[1][3]));
    float t2 = fmaxf(fmaxf(st[2][0], st[2][1]), fmaxf(st[2][2], st[2][3]));
    float t3 = fmaxf(fmaxf(st[3][0], st[3][1]), fmaxf(st[3][2], st[3][3]));
    float t = fmaxf(fmaxf(t0, t1), fmaxf(t2, t3));
    t = fmaxf(t, __shfl_xor(t, 16));
    t = fmaxf(t, __shfl_xor(t, 32));            // uniform across the q-quad

    bool resc = t > mrun + 8.f;                 // defer-max (THR=8)
    if (__any(resc)) {
      float alpha = resc ? __expf(mrun - t) : 1.f;
      if (resc) mrun = t;
      lrun *= alpha;
      // redistribute alpha to O-rows q' = (lane>>4)*4 + r
#pragma unroll
      for (int r = 0; r < 4; r++) {
        float ar = __shfl(alpha, (lane >> 4) * 4 + r);
#pragma unroll
        for (int d = 0; d < 4; d++) oacc[d][r] *= ar;
      }
    }

    float p[4][4], ps = 0.f;
#pragma unroll
    for (int kc = 0; kc < 4; kc++)
#pragma unroll
      for (int r = 0; r < 4; r++) {
        p[kc][r] = __expf(st[kc][r] - mrun);
        ps += p[kc][r];
      }
    ps += __shfl_xor(ps, 16);
    ps += __shfl_xor(ps, 32);
    lrun += ps;

    // store P: 4 packed b64 writes; kv = kc*16 + (lane>>4)*4 + r
    const int qcol = lane & 15, g4 = (lane >> 4) * 4;
#pragma unroll
    for (int kc = 0; kc < 4; kc++) {
      ushort4 pk;
      pk.x = f2bf(p[kc][0]); pk.y = f2bf(p[kc][1]);
      pk.z = f2bf(p[kc][2]); pk.w = f2bf(p[kc][3]);
      *reinterpret_cast<ushort4*>(&Ps[wv][qcol][kc * 16 + g4]) = pk;
    }
    // Ps is wave-private: DS ops within a wave are in-order -> no barrier

    // O += P V
    bf16x8 pf[2];
#pragma unroll
    for (int ks = 0; ks < 2; ks++)
      pf[ks] = *reinterpret_cast<const bf16x8*>(
          &Ps[wv][lane & 15][ks * 32 + (lane >> 4) * 8]);
    __builtin_amdgcn_s_setprio(1);
#pragma unroll
    for (int d = 0; d < 4; d++) {
#pragma unroll
      for (int ks = 0; ks < 2; ks++) {
        bf16x8 vf = *reinterpret_cast<const bf16x8*>(
            &Vt[d * 16 + (lane & 15)][ks * 32 + (lane >> 4) * 8]);
        oacc[d] = __builtin_amdgcn_mfma_f32_16x16x32_bf16(pf[ks], vf, oacc[d], 0, 0, 0);
      }
    }
    __builtin_amdgcn_s_setprio(0);
    __syncthreads();                            // protect Ks/Vt for next tile
  }

  // write O / l  -> out[b, n, h*64 + d]  (bf16); l redistributed via shfl
  int b_ = bh >> 4, hh = bh & 15;
#pragma unroll
  for (int r = 0; r < 4; r++) {
    float lr = __shfl(lrun, (lane >> 4) * 4 + r);
    float rl = 1.f / lr;
#pragma unroll
    for (int d = 0; d < 4; d++) {
      int row = q0 + wv * 16 + (lane >> 4) * 4 + r;
      int col = hh * HDIM + d * 16 + (lane & 15);
      o[((size_t)(b_ * SEQLEN + row)) * E_DIM + col] = f2bf(oacc[d][r] * rl);
    }
  }
}

extern "C" void kernel_launch(void* const* d_in, const int* in_sizes, int n_in,
                              void* d_out, int out_size, void* d_ws, size_t ws_size,
                              hipStream_t stream) {
  (void)in_sizes; (void)n_in; (void)out_size; (void)ws_size;
  const float* x      = (const float*)d_in[0];
  const float* ln1_g  = (const float*)d_in[1];
  const float* ln1_b  = (const float*)d_in[2];
  const float* qkv_w  = (const float*)d_in[3];
  const float* qkv_b  = (const float*)d_in[4];
  const float* proj_w = (const float*)d_in[5];
  const float* proj_b = (const float*)d_in[6];
  const float* ln2_g  = (const float*)d_in[7];
  const float* ln2_b  = (const float*)d_in[8];
  const float* fc1_w  = (const float*)d_in[9];
  const float* fc1_b  = (const float*)d_in[10];
  const float* fc2_w  = (const float*)d_in[11];
  const float* fc2_b  = (const float*)d_in[12];
  float* out = (float*)d_out;

  char* p = (char*)d_ws;
  auto carve = [&](size_t n) { char* r = p; p += (n + 255) & ~(size_t)255; return r; };
  bfu* qkv_wt  = (bfu*)carve((size_t)3 * E_DIM * E_DIM * 2);   // [3E, E]
  bfu* proj_wt = (bfu*)carve((size_t)E_DIM * E_DIM * 2);       // [E, E]
  bfu* fc1_wt  = (bfu*)carve((size_t)FF_DIM * E_DIM * 2);      // [FF, E]
  bfu* fc2_wt  = (bfu*)carve((size_t)E_DIM * FF_DIM * 2);      // [E, FF]
  bfu* hbuf    = (bfu*)carve((size_t)NTOK * E_DIM * 2);        // LN out (reused)
  bfu* region  = (bfu*)carve((size_t)NTOK * FF_DIM * 2);       // q,k,v,ao | h3
  float* x1    = (float*)carve((size_t)NTOK * E_DIM * 4);      // post-attn residual
  bfu* qb = region;
  bfu* kb = region + (size_t)NTOK * E_DIM;
  bfu* vb = region + (size_t)2 * NTOK * E_DIM;
  bfu* ao = region + (size_t)3 * NTOK * E_DIM;
  bfu* h3 = region;                                            // aliases q/k/v/ao

  dim3 tb(32, 8);
  transpose_cvt<<<dim3(3 * E_DIM / 32, E_DIM / 32), tb, 0, stream>>>(qkv_w, qkv_wt, E_DIM, 3 * E_DIM);
  transpose_cvt<<<dim3(E_DIM / 32, E_DIM / 32), tb, 0, stream>>>(proj_w, proj_wt, E_DIM, E_DIM);
  transpose_cvt<<<dim3(FF_DIM / 32, E_DIM / 32), tb, 0, stream>>>(fc1_w, fc1_wt, E_DIM, FF_DIM);
  transpose_cvt<<<dim3(E_DIM / 32, FF_DIM / 32), tb, 0, stream>>>(fc2_w, fc2_wt, FF_DIM, E_DIM);

  ln_kernel<<<NTOK, 256, 0, stream>>>(x, ln1_g, ln1_b, hbuf);
  gemm_kernel<0, 128><<<dim3(3 * E_DIM / 128, NTOK / 128), 256, 0, stream>>>(
      hbuf, qkv_wt, NTOK, 3 * E_DIM, E_DIM, qkv_b, nullptr, nullptr, nullptr, qb, kb, vb);
  attn_kernel<<<dim3(SEQLEN / 64, NBATCH * NHEAD), 256, 0, stream>>>(qb, kb, vb, ao);
  gemm_kernel<1, 64><<<dim3(E_DIM / 64, NTOK / 128), 256, 0, stream>>>(
      ao, proj_wt, NTOK, E_DIM, E_DIM, proj_b, x, x1, nullptr, nullptr, nullptr, nullptr);
  ln_kernel<<<NTOK, 256, 0, stream>>>(x1, ln2_g, ln2_b, hbuf);
  gemm_kernel<2, 128><<<dim3(FF_DIM / 128, NTOK / 128), 256, 0, stream>>>(
      hbuf, fc1_wt, NTOK, FF_DIM, E_DIM, fc1_b, nullptr, nullptr, h3, nullptr, nullptr, nullptr);
  gemm_kernel<3, 64><<<dim3(E_DIM / 64, NTOK / 128), 256, 0, stream>>>(
      h3, fc2_wt, NTOK, E_DIM, FF_DIM, fc2_b, x1, out, nullptr, nullptr, nullptr, nullptr);
}

// Round 8
// 359.683 us; speedup vs baseline: 1.4194x; 1.2303x over previous
//
#include <hip/hip_runtime.h>
#include <hip/hip_bf16.h>
#include <math.h>

#define E_DIM 1024
#define NHEAD 16
#define HDIM 64
#define FF_DIM 4096
#define NBATCH 2
#define SEQLEN 2048
#define NTOK 4096
#define LN_EPS 1e-5f

typedef unsigned short bfu;                                   // raw bf16 bits
typedef __attribute__((ext_vector_type(8))) short bf16x8;     // MFMA A/B frag (4 VGPR)
typedef __attribute__((ext_vector_type(4))) float f32x4;      // MFMA C/D frag

static __device__ __forceinline__ bfu f2bf(float f) {
  __hip_bfloat16 h = __float2bfloat16(f);                     // RNE, single cvt op
  return *reinterpret_cast<bfu*>(&h);
}

// async global->LDS, 16B per lane: lane l writes ldsbase + l*16 bytes.
static __device__ __forceinline__ void gld16(const bfu* g, bfu* l) {
  __builtin_amdgcn_global_load_lds(
      (const __attribute__((address_space(1))) void*)g,
      (__attribute__((address_space(3))) void*)l, 16, 0, 0);
}

// ---------------- weight transpose + fp32 -> bf16 ----------------
__global__ __launch_bounds__(256) void transpose_cvt(
    const float* __restrict__ W, bfu* __restrict__ Wt, int R, int C) {
  __shared__ float t[32][33];
  int c0 = blockIdx.x * 32, r0 = blockIdx.y * 32;
#pragma unroll
  for (int i = 0; i < 32; i += 8)
    t[threadIdx.y + i][threadIdx.x] =
        W[(size_t)(r0 + threadIdx.y + i) * C + c0 + threadIdx.x];
  __syncthreads();
#pragma unroll
  for (int i = 0; i < 32; i += 8)
    Wt[(size_t)(c0 + threadIdx.y + i) * R + r0 + threadIdx.x] =
        f2bf(t[threadIdx.x][threadIdx.y + i]);
}

// ---------------- layernorm: fp32 [rows][1024] -> bf16 ----------------
__global__ __launch_bounds__(256) void ln_kernel(
    const float* __restrict__ x, const float* __restrict__ g,
    const float* __restrict__ b, bfu* __restrict__ out) {
  int row = blockIdx.x;
  float4 v = reinterpret_cast<const float4*>(x + (size_t)row * E_DIM)[threadIdx.x];
  float s = v.x + v.y + v.z + v.w;
  float s2 = v.x * v.x + v.y * v.y + v.z * v.z + v.w * v.w;
#pragma unroll
  for (int off = 1; off < 64; off <<= 1) {
    s += __shfl_xor(s, off);
    s2 += __shfl_xor(s2, off);
  }
  __shared__ float red[8];
  int wv = threadIdx.x >> 6;
  if ((threadIdx.x & 63) == 0) { red[wv] = s; red[4 + wv] = s2; }
  __syncthreads();
  s = red[0] + red[1] + red[2] + red[3];
  s2 = red[4] + red[5] + red[6] + red[7];
  float mu = s * (1.f / E_DIM);
  float var = s2 * (1.f / E_DIM) - mu * mu;
  float rs = rsqrtf(var + LN_EPS);
  int c = threadIdx.x * 4;
  ushort4 o;
  o.x = f2bf((v.x - mu) * rs * g[c + 0] + b[c + 0]);
  o.y = f2bf((v.y - mu) * rs * g[c + 1] + b[c + 1]);
  o.z = f2bf((v.z - mu) * rs * g[c + 2] + b[c + 2]);
  o.w = f2bf((v.w - mu) * rs * g[c + 3] + b[c + 3]);
  reinterpret_cast<ushort4*>(out + (size_t)row * E_DIM)[threadIdx.x] = o;
}

// ---------------- GEMM: 2-phase dbuf (T3-min) + LDS swizzle (G21) ------------
// LDS[row][ce] holds global col (ce ^ (row&7)*8): pre-swizzled source feeding
// linear-dest global_load_lds; reads XOR the same pattern -> conflict-free.
// EP 0: qkv scatter (+bias, q*0.125)  1: proj (+bias+resid -> f32)
// EP 2: fc1 (+bias, exact gelu -> bf16)  3: fc2 (+bias+resid -> f32)
template <int EP, int BN>
__global__ __launch_bounds__(256) void gemm_kernel(
    const bfu* __restrict__ A, const bfu* __restrict__ Bt,
    int M, int N, int K,
    const float* __restrict__ bias, const float* __restrict__ resid,
    float* __restrict__ outf, bfu* __restrict__ outb,
    bfu* __restrict__ qo, bfu* __restrict__ ko, bfu* __restrict__ vo) {
  constexpr int NJ = BN / 32;                 // col frags per wave (2x2 wave grid)
  __shared__ __align__(16) bfu As[2][128][64];
  __shared__ __align__(16) bfu Bs[2][BN][64];
  const int tid = threadIdx.x;
  const int lane = tid & 63, wv = tid >> 6;
  const int wr = (wv >> 1) * 64, wc = (wv & 1) * (BN / 2);
  // XCD-aware bijective swizzle (T1): contiguous logical chunk per XCD.
  const int gx = gridDim.x, nwg = gx * gridDim.y;
  const int hw = blockIdx.y * gx + blockIdx.x;
  const int lg = (hw & 7) * (nwg >> 3) + (hw >> 3);
  const int m0 = (lg / gx) * 128, n0 = (lg % gx) * BN;

  f32x4 acc[4][NJ];
#pragma unroll
  for (int i = 0; i < 4; i++)
#pragma unroll
    for (int j = 0; j < NJ; j++) acc[i][j] = (f32x4){0.f, 0.f, 0.f, 0.f};

  const int sr = lane >> 3;                        // staging row within 8-row chunk
  const int scs = ((lane & 7) ^ (sr & 7)) * 8;     // pre-swizzled source col
  const int rsw = (lane & 7) << 3;                 // read-side XOR (row&7 == lane&7)

  auto stage = [&](int buf, int k0) {
#pragma unroll
    for (int c = 0; c < 4; c++) {               // A rows [wv*32, wv*32+32)
      int r = wv * 32 + c * 8;
      gld16(A + (size_t)(m0 + r + sr) * K + k0 + scs, &As[buf][r][0]);
    }
#pragma unroll
    for (int c = 0; c < BN / 32; c++) {         // B rows, BN/32 chunks per wave
      int r = wv * (BN / 4) + c * 8;
      gld16(Bt + (size_t)(n0 + r + sr) * K + k0 + scs, &Bs[buf][r][0]);
    }
  };

  stage(0, 0);
  __syncthreads();                              // drains vmcnt -> buf0 ready
  const int NT = K >> 6;
  int cur = 0;
  for (int t = 0; t < NT; t++) {
    if (t + 1 < NT) stage(cur ^ 1, (t + 1) * 64);   // prefetch overlaps compute
#pragma unroll
    for (int kk = 0; kk < 2; kk++) {
      const int ce = (kk * 32 + (lane >> 4) * 8) ^ rsw;
      bf16x8 af[4], bfr[NJ];
#pragma unroll
      for (int i = 0; i < 4; i++)
        af[i] = *reinterpret_cast<const bf16x8*>(&As[cur][wr + i * 16 + (lane & 15)][ce]);
#pragma unroll
      for (int j = 0; j < NJ; j++)
        bfr[j] = *reinterpret_cast<const bf16x8*>(&Bs[cur][wc + j * 16 + (lane & 15)][ce]);
#pragma unroll
      for (int i = 0; i < 4; i++)
#pragma unroll
        for (int j = 0; j < NJ; j++)
          acc[i][j] = __builtin_amdgcn_mfma_f32_16x16x32_bf16(af[i], bfr[j], acc[i][j], 0, 0, 0);
    }
    __syncthreads();                            // next buf ready; cur free to refill
    cur ^= 1;
  }

  const int cr = (lane >> 4) * 4, cc = lane & 15;
#pragma unroll
  for (int i = 0; i < 4; i++) {
#pragma unroll
    for (int j = 0; j < NJ; j++) {
      const int gn = n0 + wc + j * 16 + cc;
      const float bb = bias[gn];
#pragma unroll
      for (int r = 0; r < 4; r++) {
        const int gm = m0 + wr + i * 16 + cr + r;
        float val = acc[i][j][r] + bb;
        if (EP == 0) {
          int which = gn >> 10, rem = gn & 1023;
          int hh = rem >> 6, dd = rem & 63;
          int b_ = gm >> 11, nn = gm & 2047;
          size_t dst = (((size_t)(b_ * NHEAD + hh)) * SEQLEN + nn) * HDIM + dd;
          if (which == 0) qo[dst] = f2bf(val * 0.125f);   // fold 1/sqrt(D)
          else if (which == 1) ko[dst] = f2bf(val);
          else vo[dst] = f2bf(val);
        } else if (EP == 1) {
          outf[(size_t)gm * N + gn] = val + resid[(size_t)gm * N + gn];
        } else if (EP == 2) {
          outb[(size_t)gm * N + gn] = f2bf(0.5f * val * (1.f + erff(val * 0.70710678f)));
        } else {
          outf[(size_t)gm * N + gn] = val + resid[(size_t)gm * N + gn];
        }
      }
    }
  }
}

// ---------------- flash attention: swapped QK^T, in-lane softmax -------------
// K LDS swizzle: f(row, ce) = ce ^ ((row&7)<<3) applied on global SOURCE at
// staging (LDS dest linear for global_load_lds) and on the READ in QK^T.
// QK^T computed as mfma(K, Q) -> S^T: lane holds S[kv(16 vals)][q=lane&15];
// softmax is in-lane + 2 shfl_xor; P stored as 4x ds_write_b64 (wave-private).
__global__ __launch_bounds__(256) void attn_kernel(
    const bfu* __restrict__ q, const bfu* __restrict__ kbuf,
    const bfu* __restrict__ vbuf, bfu* __restrict__ o) {
  __shared__ __align__(16) bfu Ks[64][64];      // linear (global_load_lds dest)
  __shared__ __align__(16) bfu Vt[64][72];      // V^T tile [d][kv], pad 8
  __shared__ __align__(16) bfu Ps[4][16][72];   // per-wave P [q][kv], pad 8

  // XCD swizzle: group q-tiles of the same head on one XCD (K/V L2 reuse)
  const int hw = blockIdx.y * gridDim.x + blockIdx.x;   // grid (32, 32)
  const int lg = (hw & 7) * 128 + (hw >> 3);
  const int bh = lg >> 5;                       // b*H + h
  const int q0 = (lg & 31) * 64;
  const int tid = threadIdx.x, lane = tid & 63, wv = tid >> 6;
  const size_t base = (size_t)bh * SEQLEN * HDIM;
  const bfu* qp = q + base;
  const bfu* kp = kbuf + base;
  const bfu* vp = vbuf + base;

  // Q fragments for this wave's 16 rows (pre-scaled by 1/8 at qkv epilogue)
  const int qr = q0 + wv * 16 + (lane & 15);
  bf16x8 qf[2];
  qf[0] = *reinterpret_cast<const bf16x8*>(qp + (size_t)qr * HDIM + (lane >> 4) * 8);
  qf[1] = *reinterpret_cast<const bf16x8*>(qp + (size_t)qr * HDIM + 32 + (lane >> 4) * 8);

  float mrun = -1e30f, lrun = 0.f;              // softmax state for q = lane&15
  f32x4 oacc[4];                                // O rows q' = (lane>>4)*4+r
#pragma unroll
  for (int d = 0; d < 4; d++) oacc[d] = (f32x4){0.f, 0.f, 0.f, 0.f};

  const int sr = lane >> 3;                          // K staging row within chunk
  const int scs = ((lane & 7) ^ (sr & 7)) * 8;       // pre-swizzled source col
  const int vrow = tid & 63, vcb = (tid >> 6) * 16;  // V staging

  for (int kt = 0; kt < SEQLEN; kt += 64) {
    // K tile via async DMA: wave wv stages chunks {2wv, 2wv+1} (8 rows each)
#pragma unroll
    for (int c = 0; c < 2; c++) {
      int ch = wv * 2 + c;
      gld16(kp + (size_t)(kt + ch * 8 + sr) * HDIM + scs, &Ks[ch * 8][0]);
    }
    // V tile: reg-staged transpose; writes conflict-free (64 lanes span a row)
    bf16x8 v0 = *reinterpret_cast<const bf16x8*>(vp + (size_t)(kt + vrow) * HDIM + vcb);
    bf16x8 v1 = *reinterpret_cast<const bf16x8*>(vp + (size_t)(kt + vrow) * HDIM + vcb + 8);
#pragma unroll
    for (int j = 0; j < 8; j++) {
      Vt[vcb + j][vrow] = (bfu)(unsigned short)v0[j];
      Vt[vcb + 8 + j][vrow] = (bfu)(unsigned short)v1[j];
    }
    __syncthreads();

    // S^T[kv][q] = mfma(K, Q): st[kc][r] = S[kv=kc*16+(lane>>4)*4+r][q=lane&15]
    f32x4 st[4];
    __builtin_amdgcn_s_setprio(1);
#pragma unroll
    for (int kc = 0; kc < 4; kc++) {
      f32x4 a = (f32x4){0.f, 0.f, 0.f, 0.f};
#pragma unroll
      for (int kk = 0; kk < 2; kk++) {
        int ce = (kk * 32 + (lane >> 4) * 8) ^ ((lane & 7) << 3);
        bf16x8 kf = *reinterpret_cast<const bf16x8*>(&Ks[kc * 16 + (lane & 15)][ce]);
        a = __builtin_amdgcn_mfma_f32_16x16x32_bf16(kf, qf[kk], a, 0, 0, 0);
      }
      st[kc] = a;
    }
    __builtin_amdgcn_s_setprio(0);

    // in-lane softmax over the 16 kv values, then 2 shfls to span all 64 kv
    float t0 = fmaxf(fmaxf(st[0][0], st[0][1]), fmaxf(st[0][2], st[0][3]));
    float t1 = fmaxf(fmaxf(st[1][0], st[1][1]), fmaxf(st[1][2], st[1][3]));
    float t2 = fmaxf(fmaxf(st[2][0], st[2][1]), fmaxf(st[2][2], st[2][3]));
    float t3 = fmaxf(fmaxf(st[3][0], st[3][1]), fmaxf(st[3][2], st[3][3]));
    float t = fmaxf(fmaxf(t0, t1), fmaxf(t2, t3));
    t = fmaxf(t, __shfl_xor(t, 16));
    t = fmaxf(t, __shfl_xor(t, 32));            // uniform across the q-quad

    bool resc = t > mrun + 8.f;                 // defer-max (THR=8)
    if (__any(resc)) {
      float alpha = resc ? __expf(mrun - t) : 1.f;
      if (resc) mrun = t;
      lrun *= alpha;
      // redistribute alpha to O-rows q' = (lane>>4)*4 + r
#pragma unroll
      for (int r = 0; r < 4; r++) {
        float ar = __shfl(alpha, (lane >> 4) * 4 + r);
#pragma unroll
        for (int d = 0; d < 4; d++) oacc[d][r] *= ar;
      }
    }

    float p[4][4], ps = 0.f;
#pragma unroll
    for (int kc = 0; kc < 4; kc++)
#pragma unroll
      for (int r = 0; r < 4; r++) {
        p[kc][r] = __expf(st[kc][r] - mrun);
        ps += p[kc][r];
      }
    ps += __shfl_xor(ps, 16);
    ps += __shfl_xor(ps, 32);
    lrun += ps;

    // store P: 4 packed b64 writes; kv = kc*16 + (lane>>4)*4 + r
    const int qcol = lane & 15, g4 = (lane >> 4) * 4;
#pragma unroll
    for (int kc = 0; kc < 4; kc++) {
      ushort4 pk;
      pk.x = f2bf(p[kc][0]); pk.y = f2bf(p[kc][1]);
      pk.z = f2bf(p[kc][2]); pk.w = f2bf(p[kc][3]);
      *reinterpret_cast<ushort4*>(&Ps[wv][qcol][kc * 16 + g4]) = pk;
    }
    // Ps is wave-private: DS ops within a wave are in-order -> no barrier

    // O += P V
    bf16x8 pf[2];
#pragma unroll
    for (int ks = 0; ks < 2; ks++)
      pf[ks] = *reinterpret_cast<const bf16x8*>(
          &Ps[wv][lane & 15][ks * 32 + (lane >> 4) * 8]);
    __builtin_amdgcn_s_setprio(1);
#pragma unroll
    for (int d = 0; d < 4; d++) {
#pragma unroll
      for (int ks = 0; ks < 2; ks++) {
        bf16x8 vf = *reinterpret_cast<const bf16x8*>(
            &Vt[d * 16 + (lane & 15)][ks * 32 + (lane >> 4) * 8]);
        oacc[d] = __builtin_amdgcn_mfma_f32_16x16x32_bf16(pf[ks], vf, oacc[d], 0, 0, 0);
      }
    }
    __builtin_amdgcn_s_setprio(0);
    __syncthreads();                            // protect Ks/Vt for next tile
  }

  // write O / l  -> out[b, n, h*64 + d]  (bf16); l redistributed via shfl
  int b_ = bh >> 4, hh = bh & 15;
#pragma unroll
  for (int r = 0; r < 4; r++) {
    float lr = __shfl(lrun, (lane >> 4) * 4 + r);
    float rl = 1.f / lr;
#pragma unroll
    for (int d = 0; d < 4; d++) {
      int row = q0 + wv * 16 + (lane >> 4) * 4 + r;
      int col = hh * HDIM + d * 16 + (lane & 15);
      o[((size_t)(b_ * SEQLEN + row)) * E_DIM + col] = f2bf(oacc[d][r] * rl);
    }
  }
}

extern "C" void kernel_launch(void* const* d_in, const int* in_sizes, int n_in,
                              void* d_out, int out_size, void* d_ws, size_t ws_size,
                              hipStream_t stream) {
  (void)in_sizes; (void)n_in; (void)out_size; (void)ws_size;
  const float* x      = (const float*)d_in[0];
  const float* ln1_g  = (const float*)d_in[1];
  const float* ln1_b  = (const float*)d_in[2];
  const float* qkv_w  = (const float*)d_in[3];
  const float* qkv_b  = (const float*)d_in[4];
  const float* proj_w = (const float*)d_in[5];
  const float* proj_b = (const float*)d_in[6];
  const float* ln2_g  = (const float*)d_in[7];
  const float* ln2_b  = (const float*)d_in[8];
  const float* fc1_w  = (const float*)d_in[9];
  const float* fc1_b  = (const float*)d_in[10];
  const float* fc2_w  = (const float*)d_in[11];
  const float* fc2_b  = (const float*)d_in[12];
  float* out = (float*)d_out;

  char* p = (char*)d_ws;
  auto carve = [&](size_t n) { char* r = p; p += (n + 255) & ~(size_t)255; return r; };
  bfu* qkv_wt  = (bfu*)carve((size_t)3 * E_DIM * E_DIM * 2);   // [3E, E]
  bfu* proj_wt = (bfu*)carve((size_t)E_DIM * E_DIM * 2);       // [E, E]
  bfu* fc1_wt  = (bfu*)carve((size_t)FF_DIM * E_DIM * 2);      // [FF, E]
  bfu* fc2_wt  = (bfu*)carve((size_t)E_DIM * FF_DIM * 2);      // [E, FF]
  bfu* hbuf    = (bfu*)carve((size_t)NTOK * E_DIM * 2);        // LN out (reused)
  bfu* region  = (bfu*)carve((size_t)NTOK * FF_DIM * 2);       // q,k,v,ao | h3
  float* x1    = (float*)carve((size_t)NTOK * E_DIM * 4);      // post-attn residual
  bfu* qb = region;
  bfu* kb = region + (size_t)NTOK * E_DIM;
  bfu* vb = region + (size_t)2 * NTOK * E_DIM;
  bfu* ao = region + (size_t)3 * NTOK * E_DIM;
  bfu* h3 = region;                                            // aliases q/k/v/ao

  dim3 tb(32, 8);
  transpose_cvt<<<dim3(3 * E_DIM / 32, E_DIM / 32), tb, 0, stream>>>(qkv_w, qkv_wt, E_DIM, 3 * E_DIM);
  transpose_cvt<<<dim3(E_DIM / 32, E_DIM / 32), tb, 0, stream>>>(proj_w, proj_wt, E_DIM, E_DIM);
  transpose_cvt<<<dim3(FF_DIM / 32, E_DIM / 32), tb, 0, stream>>>(fc1_w, fc1_wt, E_DIM, FF_DIM);
  transpose_cvt<<<dim3(E_DIM / 32, FF_DIM / 32), tb, 0, stream>>>(fc2_w, fc2_wt, FF_DIM, E_DIM);

  ln_kernel<<<NTOK, 256, 0, stream>>>(x, ln1_g, ln1_b, hbuf);
  gemm_kernel<0, 128><<<dim3(3 * E_DIM / 128, NTOK / 128), 256, 0, stream>>>(
      hbuf, qkv_wt, NTOK, 3 * E_DIM, E_DIM, qkv_b, nullptr, nullptr, nullptr, qb, kb, vb);
  attn_kernel<<<dim3(SEQLEN / 64, NBATCH * NHEAD), 256, 0, stream>>>(qb, kb, vb, ao);
  gemm_kernel<1, 64><<<dim3(E_DIM / 64, NTOK / 128), 256, 0, stream>>>(
      ao, proj_wt, NTOK, E_DIM, E_DIM, proj_b, x, x1, nullptr, nullptr, nullptr, nullptr);
  ln_kernel<<<NTOK, 256, 0, stream>>>(x1, ln2_g, ln2_b, hbuf);
  gemm_kernel<2, 128><<<dim3(FF_DIM / 128, NTOK / 128), 256, 0, stream>>>(
      hbuf, fc1_wt, NTOK, FF_DIM, E_DIM, fc1_b, nullptr, nullptr, h3, nullptr, nullptr, nullptr);
  gemm_kernel<3, 64><<<dim3(E_DIM / 64, NTOK / 128), 256, 0, stream>>>(
      h3, fc2_wt, NTOK, E_DIM, FF_DIM, fc2_b, x1, out, nullptr, nullptr, nullptr, nullptr);
}